// Round 4
// baseline (62439.044 us; speedup 1.0000x reference)
//
#include <hip/hip_runtime.h>
#include <hip/hip_bf16.h>
#include <math.h>

// ---------------- problem constants ----------------
#define BATCH 200
#define T_FEAT 2048
#define F_DIM 128
#define T_CHAR 128
#define EMB_D 150
#define VOCAB 5000
#define H_FEAT 256
#define H_CHAR 200
#define HID 264
#define NCLS 8

// ---------------- persistent GRU geometry ----------------
#define NGRP 8           // batch groups of 25 rows; group = blockIdx&7 (XCD-local)
#define TBR 25           // batch rows per group
#define FBPG 32          // feature blocks per group (8 units each)
#define CBPG 25          // char blocks per group (8 units each)
#define FLAG_STRIDE 16   // uints between flags (64 B)

// ---------------------------------------------------------------------------
// prep: fused+transposed recurrent weights WT[3H][XPAD+H]
//   row c (= gate-column index in [0,3H)) = [ W[0:D,c] | 0 | U[0:H,c] ]
// ---------------------------------------------------------------------------
__global__ void prep_wt(const float* __restrict__ W, const float* __restrict__ U,
                        float* __restrict__ WT, int D, int XPAD, int H)
{
    const int DHp = XPAD + H;
    const int total = 3 * H * DHp;
    int idx = blockIdx.x * blockDim.x + threadIdx.x;
    if (idx >= total) return;
    int c = idx / DHp;
    int d = idx % DHp;
    float v;
    if (d < D)          v = W[(size_t)d * (3 * H) + c];
    else if (d < XPAD)  v = 0.f;
    else                v = U[(size_t)(d - XPAD) * (3 * H) + c];
    WT[idx] = v;
}

// pad emb table to 152 cols (zeros) so K-loops are clean float4
__global__ void prep_emb(const float* __restrict__ emb, float* __restrict__ embP)
{
    int idx = blockIdx.x * blockDim.x + threadIdx.x;
    const int total = VOCAB * 152;
    if (idx >= total) return;
    int v = idx / 152, d = idx % 152;
    embP[idx] = (d < EMB_D) ? emb[(size_t)v * EMB_D + d] : 0.f;
}

// ---------------------------------------------------------------------------
// Merged persistent GRU (cooperative, 256 blocks x 512 threads).
//   Feature: group bc=blk&7, unit-chunk uc=blk>>3 (32 chunks of 8 units).
//   Char:    same groups; blocks with uc<25 carry 8 char units each,
//            time-multiplexed during the first 128 iterations.
//   Sync: per-block monotonic flags (agent scope), wave0 polls w/ s_sleep.
//   h: double-buffered global, agent-scope stores, plain loads after
//      acquire fence. x(feat) raw-prefetched 1 step ahead into registers.
// ---------------------------------------------------------------------------
__launch_bounds__(512, 1)
__global__ void gru_both(const float* __restrict__ feat,
                         const int*   __restrict__ cids,
                         const float* __restrict__ embP,
                         const float* __restrict__ WTf,   // [768][384]
                         const float* __restrict__ WTc,   // [600][352]
                         const float* __restrict__ bf0, const float* __restrict__ bf1,
                         const float* __restrict__ bc0, const float* __restrict__ bc1,
                         float* __restrict__ hfA, float* __restrict__ hfB,
                         float* __restrict__ hcA, float* __restrict__ hcB,
                         unsigned* __restrict__ flagsF,
                         unsigned* __restrict__ flagsC)
{
    __shared__ float wF[24][388];     // 37.25 KB (388%32==4 -> conflict-free)
    __shared__ float wC[24][356];     // 34.2 KB
    __shared__ float px[256 * 5];     // 5 KB partial exchange

    const int tid = threadIdx.x;
    const int bc  = blockIdx.x & 7;        // group (XCD-local under round-robin)
    const int uc  = blockIdx.x >> 3;       // unit chunk
    const int bg  = bc * TBR;
    const int ugF = uc * 8;
    const bool hasChar = (uc < CBPG);
    const int ugC = uc * 8;

    // ---- stage weight slices once ----
    for (int i = tid; i < 24 * 96; i += 512) {
        int r = i / 96, d4 = (i % 96) * 4;
        int wrow = (r >> 3) * H_FEAT + ugF + (r & 7);
        *reinterpret_cast<float4*>(&wF[r][d4]) =
            *reinterpret_cast<const float4*>(WTf + (size_t)wrow * 384 + d4);
    }
    if (hasChar) {
        for (int i = tid; i < 24 * 88; i += 512) {
            int r = i / 88, d4 = (i % 88) * 4;
            int wrow = (r >> 3) * H_CHAR + ugC + (r & 7);
            *reinterpret_cast<float4*>(&wC[r][d4]) =
                *reinterpret_cast<const float4*>(WTc + (size_t)wrow * 352 + d4);
        }
    }

    const int k = tid >> 8;            // K-split half
    const int pairIdx = tid & 255;
    const int j = pairIdx & 7;
    const int b = pairIdx >> 3;
    const bool valid = (b < TBR);

    // LDS weight row pointers
    const float* wzF = wF[j];
    const float* wrF = wF[8 + j];
    const float* whF = wF[16 + j];
    const float* wzC = wC[j];
    const float* wrC = wC[8 + j];
    const float* whC = wC[16 + j];

    // bias combos
    const float bzzF = bf0[ugF + j] + bf1[ugF + j];
    const float brrF = bf0[H_FEAT + ugF + j] + bf1[H_FEAT + ugF + j];
    const float bxhF = bf0[2 * H_FEAT + ugF + j];
    const float brhF = bf1[2 * H_FEAT + ugF + j];
    float bzzC = 0.f, brrC = 0.f, bxhC = 0.f, brhC = 0.f;
    if (hasChar) {
        bzzC = bc0[ugC + j] + bc1[ugC + j];
        brrC = bc0[H_CHAR + ugC + j] + bc1[H_CHAR + ugC + j];
        bxhC = bc0[2 * H_CHAR + ugC + j];
        brhC = bc1[2 * H_CHAR + ugC + j];
    }

    unsigned* gfF = flagsF + (size_t)bc * 32 * FLAG_STRIDE;
    unsigned* gfC = flagsC + (size_t)bc * 32 * FLAG_STRIDE;
    unsigned* myF = gfF + (size_t)uc * FLAG_STRIDE;
    unsigned* myC = gfC + (size_t)uc * FLAG_STRIDE;

    __syncthreads();                   // weights staged

    // ---- pre-loop: feat xdot(0), raw x(1); char xdot(0) ----
    float xaz = 0.f, xar = 0.f, xah = 0.f;     // feat x-dot for current t
    float4 rawF[16];
    if (valid) {
        const float* x0 = feat + ((size_t)(bg + b) * T_FEAT + 0) * F_DIM + k * 64;
        #pragma unroll
        for (int i = 0; i < 16; ++i) {
            float4 xv = reinterpret_cast<const float4*>(x0)[i];
            float4 a4 = *reinterpret_cast<const float4*>(wzF + 4 * i + k * 64);
            float4 c4 = *reinterpret_cast<const float4*>(wrF + 4 * i + k * 64);
            float4 e4 = *reinterpret_cast<const float4*>(whF + 4 * i + k * 64);
            xaz += xv.x*a4.x + xv.y*a4.y + xv.z*a4.z + xv.w*a4.w;
            xar += xv.x*c4.x + xv.y*c4.y + xv.z*c4.z + xv.w*c4.w;
            xah += xv.x*e4.x + xv.y*e4.y + xv.z*e4.z + xv.w*e4.w;
        }
        const float* x1 = feat + ((size_t)(bg + b) * T_FEAT + 1) * F_DIM + k * 64;
        #pragma unroll
        for (int i = 0; i < 16; ++i) rawF[i] = reinterpret_cast<const float4*>(x1)[i];
    }
    float cxaz = 0.f, cxar = 0.f, cxah = 0.f;  // char x-dot for current t
    if (hasChar && valid) {
        int id0 = cids[(size_t)(bg + b) * T_CHAR + 0];
        const float* e0 = embP + (size_t)id0 * 152 + k * 76;
        #pragma unroll
        for (int i = 0; i < 19; ++i) {
            float4 xv = reinterpret_cast<const float4*>(e0)[i];
            float4 a4 = *reinterpret_cast<const float4*>(wzC + 4 * i + k * 76);
            float4 c4 = *reinterpret_cast<const float4*>(wrC + 4 * i + k * 76);
            float4 e4 = *reinterpret_cast<const float4*>(whC + 4 * i + k * 76);
            cxaz += xv.x*a4.x + xv.y*a4.y + xv.z*a4.z + xv.w*a4.w;
            cxar += xv.x*c4.x + xv.y*c4.y + xv.z*c4.z + xv.w*c4.w;
            cxah += xv.x*e4.x + xv.y*e4.y + xv.z*e4.z + xv.w*e4.w;
        }
    }

    float holdF = 0.f, holdC = 0.f;

    for (int t = 0; t < T_FEAT; ++t) {
        const float* hfin = (t & 1) ? hfB : hfA;
        float*       hfout = (t & 1) ? hfA : hfB;
        const bool doChar = hasChar && (t < T_CHAR);

        // ---- wait for h(t) (feat; + char while active) ----
        if (t > 0) {
            if (tid < 64) {
                const unsigned tgt = (unsigned)t;
                const bool needF = (tid < FBPG);
                const bool needC = hasChar && (t < T_CHAR) &&
                                   (tid >= 32) && (tid < 32 + CBPG);
                unsigned* fp = needF ? (gfF + (size_t)tid * FLAG_STRIDE)
                             : (needC ? (gfC + (size_t)(tid - 32) * FLAG_STRIDE)
                                      : nullptr);
                for (;;) {
                    unsigned v = fp ? __hip_atomic_load(fp, __ATOMIC_RELAXED,
                                                        __HIP_MEMORY_SCOPE_AGENT)
                                    : tgt;
                    if (__all((int)(v >= tgt))) break;
                    __builtin_amdgcn_s_sleep(1);
                }
            }
            __syncthreads();
            __builtin_amdgcn_fence(__ATOMIC_ACQUIRE, "agent");
        }

        // ================= FEATURE step =================
        float haz = 0.f, har = 0.f, hah = 0.f;
        if (valid) {
            const float* hrow = hfin + (size_t)(bg + b) * H_FEAT + k * 128;
            #pragma unroll 4
            for (int i = 0; i < 32; ++i) {
                float4 hv = reinterpret_cast<const float4*>(hrow)[i];
                float4 a4 = *reinterpret_cast<const float4*>(wzF + 128 + k * 128 + 4 * i);
                float4 c4 = *reinterpret_cast<const float4*>(wrF + 128 + k * 128 + 4 * i);
                float4 e4 = *reinterpret_cast<const float4*>(whF + 128 + k * 128 + 4 * i);
                haz += hv.x*a4.x + hv.y*a4.y + hv.z*a4.z + hv.w*a4.w;
                har += hv.x*c4.x + hv.y*c4.y + hv.z*c4.z + hv.w*c4.w;
                hah += hv.x*e4.x + hv.y*e4.y + hv.z*e4.z + hv.w*e4.w;
            }
        }
        const float azs = xaz + haz, ars = xar + har;
        if (valid && k == 1) {
            float* p = &px[pairIdx * 5];
            p[0] = azs; p[1] = ars; p[2] = xah; p[3] = hah;
        }
        __syncthreads();
        if (valid && k == 0) {
            const float* p = &px[pairIdx * 5];
            float az = azs + p[0];
            float ar = ars + p[1];
            float xh = xah + p[2];
            float rh = hah + p[3];
            float z = 1.f / (1.f + __expf(-(az + bzzF)));
            float r = 1.f / (1.f + __expf(-(ar + brrF)));
            float a = xh + bxhF + r * (rh + brhF);
            float hh = 1.f - 2.f / (1.f + __expf(2.f * a));
            float hnew = z * holdF + (1.f - z) * hh;
            holdF = hnew;
            __hip_atomic_store(hfout + (size_t)(bg + b) * H_FEAT + ugF + j, hnew,
                               __ATOMIC_RELAXED, __HIP_MEMORY_SCOPE_AGENT);
        }
        __syncthreads();               // drains vmcnt -> h stores visible
        if (tid == 0 && t + 1 < T_FEAT)
            __hip_atomic_store(myF, (unsigned)(t + 1),
                               __ATOMIC_RELAXED, __HIP_MEMORY_SCOPE_AGENT);

        // feat xdot(t+1) from prefetched regs; issue raw loads for t+2
        if (valid && t + 1 < T_FEAT) {
            float nz = 0.f, nr = 0.f, nh = 0.f;
            #pragma unroll
            for (int i = 0; i < 16; ++i) {
                float4 xv = rawF[i];
                float4 a4 = *reinterpret_cast<const float4*>(wzF + 4 * i + k * 64);
                float4 c4 = *reinterpret_cast<const float4*>(wrF + 4 * i + k * 64);
                float4 e4 = *reinterpret_cast<const float4*>(whF + 4 * i + k * 64);
                nz += xv.x*a4.x + xv.y*a4.y + xv.z*a4.z + xv.w*a4.w;
                nr += xv.x*c4.x + xv.y*c4.y + xv.z*c4.z + xv.w*c4.w;
                nh += xv.x*e4.x + xv.y*e4.y + xv.z*e4.z + xv.w*e4.w;
            }
            xaz = nz; xar = nr; xah = nh;
            if (t + 2 < T_FEAT) {
                const float* xn = feat + ((size_t)(bg + b) * T_FEAT + (t + 2)) * F_DIM + k * 64;
                #pragma unroll
                for (int i = 0; i < 16; ++i) rawF[i] = reinterpret_cast<const float4*>(xn)[i];
            }
        }

        // ================= CHAR step (first 128 iters) =================
        if (doChar) {
            const float* hcin = (t & 1) ? hcB : hcA;
            float*       hcout = (t & 1) ? hcA : hcB;
            int idN = 0;
            if (valid && t + 1 < T_CHAR)
                idN = cids[(size_t)(bg + b) * T_CHAR + (t + 1)];

            float chaz = 0.f, char_ = 0.f, chah = 0.f;
            if (valid) {
                const float* hrow = hcin + (size_t)(bg + b) * H_CHAR + k * 100;
                #pragma unroll 5
                for (int i = 0; i < 25; ++i) {
                    float4 hv = reinterpret_cast<const float4*>(hrow)[i];
                    float4 a4 = *reinterpret_cast<const float4*>(wzC + 152 + k * 100 + 4 * i);
                    float4 c4 = *reinterpret_cast<const float4*>(wrC + 152 + k * 100 + 4 * i);
                    float4 e4 = *reinterpret_cast<const float4*>(whC + 152 + k * 100 + 4 * i);
                    chaz  += hv.x*a4.x + hv.y*a4.y + hv.z*a4.z + hv.w*a4.w;
                    char_ += hv.x*c4.x + hv.y*c4.y + hv.z*c4.z + hv.w*c4.w;
                    chah  += hv.x*e4.x + hv.y*e4.y + hv.z*e4.z + hv.w*e4.w;
                }
            }
            const float cazs = cxaz + chaz, cars = cxar + char_;
            if (valid && k == 1) {
                float* p = &px[pairIdx * 5];
                p[0] = cazs; p[1] = cars; p[2] = cxah; p[3] = chah;
            }
            __syncthreads();
            if (valid && k == 0) {
                const float* p = &px[pairIdx * 5];
                float az = cazs + p[0];
                float ar = cars + p[1];
                float xh = cxah + p[2];
                float rh = chah + p[3];
                float z = 1.f / (1.f + __expf(-(az + bzzC)));
                float r = 1.f / (1.f + __expf(-(ar + brrC)));
                float a = xh + bxhC + r * (rh + brhC);
                float hh = 1.f - 2.f / (1.f + __expf(2.f * a));
                float hnew = z * holdC + (1.f - z) * hh;
                holdC = hnew;
                __hip_atomic_store(hcout + (size_t)(bg + b) * H_CHAR + ugC + j, hnew,
                                   __ATOMIC_RELAXED, __HIP_MEMORY_SCOPE_AGENT);
            }
            __syncthreads();
            if (tid == 0 && t + 1 < T_CHAR)
                __hip_atomic_store(myC, (unsigned)(t + 1),
                                   __ATOMIC_RELAXED, __HIP_MEMORY_SCOPE_AGENT);

            // char xdot(t+1) via L2-cached emb rows (id prefetched)
            if (valid && t + 1 < T_CHAR) {
                const float* e1 = embP + (size_t)idN * 152 + k * 76;
                float nz = 0.f, nr = 0.f, nh = 0.f;
                #pragma unroll
                for (int i = 0; i < 19; ++i) {
                    float4 xv = reinterpret_cast<const float4*>(e1)[i];
                    float4 a4 = *reinterpret_cast<const float4*>(wzC + 4 * i + k * 76);
                    float4 c4 = *reinterpret_cast<const float4*>(wrC + 4 * i + k * 76);
                    float4 e4 = *reinterpret_cast<const float4*>(whC + 4 * i + k * 76);
                    nz += xv.x*a4.x + xv.y*a4.y + xv.z*a4.z + xv.w*a4.w;
                    nr += xv.x*c4.x + xv.y*c4.y + xv.z*c4.z + xv.w*c4.w;
                    nh += xv.x*e4.x + xv.y*e4.y + xv.z*e4.z + xv.w*e4.w;
                }
                cxaz = nz; cxar = nr; cxah = nh;
            }
        }
    }
}

// ---------------------------------------------------------------------------
// dense: y[row] = act(x[row] @ W + bias). ACT: 0 none, 1 relu, 2 softmax
// ---------------------------------------------------------------------------
template<int ACT>
__launch_bounds__(256)
__global__ void dense(const float* __restrict__ x, int ldx, int D,
                      const float* __restrict__ W, const float* __restrict__ bias, int N,
                      float* __restrict__ y, int ldy)
{
    __shared__ float xs[544];
    __shared__ float ys[288];
    __shared__ float red[2];
    const int row = blockIdx.x;
    const float* xr = x + (size_t)row * ldx;
    for (int i = threadIdx.x; i < D; i += blockDim.x) xs[i] = xr[i];
    __syncthreads();
    for (int j = threadIdx.x; j < N; j += blockDim.x) {
        float acc = bias[j];
        for (int d = 0; d < D; ++d) acc += xs[d] * W[(size_t)d * N + j];
        if (ACT == 1) acc = fmaxf(acc, 0.f);
        if (ACT == 2) ys[j] = acc;
        else          y[(size_t)row * ldy + j] = acc;
    }
    if (ACT == 2) {
        __syncthreads();
        if (threadIdx.x == 0) {
            float m = -1e30f;
            for (int i = 0; i < N; ++i) m = fmaxf(m, ys[i]);
            float s = 0.f;
            for (int i = 0; i < N; ++i) s += expf(ys[i] - m);
            red[0] = m; red[1] = s;
        }
        __syncthreads();
        float m = red[0], s = red[1];
        for (int j = threadIdx.x; j < N; j += blockDim.x)
            y[(size_t)row * ldy + j] = expf(ys[j] - m) / s;
    }
}

// ---------------------------------------------------------------------------
extern "C" void kernel_launch(void* const* d_in, const int* in_sizes, int n_in,
                              void* d_out, int out_size, void* d_ws, size_t ws_size,
                              hipStream_t stream)
{
    const float* feat = (const float*)d_in[1];
    const int*   cids = (const int*)  d_in[2];
    const float* emb  = (const float*)d_in[3];
    const float* Wc   = (const float*)d_in[4];
    const float* Uc   = (const float*)d_in[5];
    const float* bcb  = (const float*)d_in[6];
    const float* Wf   = (const float*)d_in[7];
    const float* Uf   = (const float*)d_in[8];
    const float* bfb  = (const float*)d_in[9];
    const float* Wfd  = (const float*)d_in[10]; const float* bfd = (const float*)d_in[11];
    const float* Wc1  = (const float*)d_in[12]; const float* bc1 = (const float*)d_in[13];
    const float* Wc2  = (const float*)d_in[14]; const float* bc2 = (const float*)d_in[15];
    const float* W1   = (const float*)d_in[16]; const float* b1  = (const float*)d_in[17];
    const float* W2   = (const float*)d_in[18]; const float* b2  = (const float*)d_in[19];
    const float* Wsm  = (const float*)d_in[20]; const float* bsm = (const float*)d_in[21];
    float* out = (float*)d_out;

    // workspace carve-up (floats), ~6.6 MB total
    float* ws  = (float*)d_ws;
    float* WTf = ws; ws += 768 * 384;
    float* WTc = ws; ws += 600 * 352;
    float* embP = ws; ws += VOCAB * 152;
    float* hf0 = ws; ws += BATCH * H_FEAT;
    float* hf1 = ws; ws += BATCH * H_FEAT;
    float* hc0 = ws; ws += BATCH * H_CHAR;
    float* hc1 = ws; ws += BATCH * H_CHAR;
    float* xcat = ws; ws += BATCH * (2 * HID);
    float* tA  = ws; ws += BATCH * HID;
    float* tB  = ws; ws += BATCH * HID;
    unsigned* flagsF = (unsigned*)ws; ws += NGRP * 32 * FLAG_STRIDE;
    unsigned* flagsC = (unsigned*)ws; ws += NGRP * 32 * FLAG_STRIDE;

    hipMemsetAsync(hf0, 0, BATCH * H_FEAT * sizeof(float), stream);
    hipMemsetAsync(hc0, 0, BATCH * H_CHAR * sizeof(float), stream);
    hipMemsetAsync(flagsF, 0, NGRP * 32 * FLAG_STRIDE * sizeof(unsigned) * 2, stream);

    prep_wt<<<(768 * 384 + 255) / 256, 256, 0, stream>>>(Wf, Uf, WTf, 128, 128, H_FEAT);
    prep_wt<<<(600 * 352 + 255) / 256, 256, 0, stream>>>(Wc, Uc, WTc, 150, 152, H_CHAR);
    prep_emb<<<(VOCAB * 152 + 255) / 256, 256, 0, stream>>>(emb, embP);

    // ---- merged persistent GRUs: one cooperative launch, 256 blocks ----
    {
        const float* b0f = bfb;
        const float* b1f = bfb + 3 * H_FEAT;
        const float* b0c = bcb;
        const float* b1c = bcb + 3 * H_CHAR;
        void* args[] = { (void*)&feat, (void*)&cids, (void*)&embP,
                         (void*)&WTf, (void*)&WTc,
                         (void*)&b0f, (void*)&b1f, (void*)&b0c, (void*)&b1c,
                         (void*)&hf0, (void*)&hf1, (void*)&hc0, (void*)&hc1,
                         (void*)&flagsF, (void*)&flagsC };
        hipLaunchCooperativeKernel((void*)gru_both,
                                   dim3(NGRP * FBPG), dim3(512), args, 0, stream);
    }
    // both T even -> final states in buffer 0

    // ---- heads ----
    dense<1><<<BATCH, 256, 0, stream>>>(hf0, H_FEAT, H_FEAT, Wfd, bfd, HID, xcat,       2 * HID);
    dense<1><<<BATCH, 256, 0, stream>>>(hc0, H_CHAR, H_CHAR, Wc1, bc1, HID, tA,         HID);
    dense<2><<<BATCH, 256, 0, stream>>>(tA,  HID,    HID,    Wc2, bc2, HID, xcat + HID, 2 * HID);
    dense<1><<<BATCH, 256, 0, stream>>>(xcat, 2 * HID, 2 * HID, W1, b1, HID, tB,        HID);
    dense<1><<<BATCH, 256, 0, stream>>>(tB,  HID,    HID,    W2,  b2,  HID, tA,         HID);
    dense<2><<<BATCH, 256, 0, stream>>>(tA,  HID,    HID,    Wsm, bsm, NCLS, out,       NCLS);
}

// Round 5
// 43500.266 us; speedup vs baseline: 1.4354x; 1.4354x over previous
//
#include <hip/hip_runtime.h>
#include <hip/hip_bf16.h>
#include <math.h>

// ---------------- problem constants ----------------
#define BATCH 200
#define T_FEAT 2048
#define F_DIM 128
#define T_CHAR 128
#define EMB_D 150
#define VOCAB 5000
#define H_FEAT 256
#define H_CHAR 200
#define HID 264
#define NCLS 8

// ---------------- persistent GRU geometry ----------------
#define NGRP 8           // batch groups of 25 rows; group = blockIdx&7
#define TBR 25           // batch rows per group
#define FBPG 32          // feature blocks per group (8 units each)
#define CBPG 25          // char blocks per group (8 units each)
#define FLAG_STRIDE 16   // uints between flags (64 B)

// ---------------------------------------------------------------------------
// prep: fused+transposed recurrent weights WT[3H][XPAD+H]
//   row c = [ W[0:D,c] | 0 | U[0:H,c] ]
// ---------------------------------------------------------------------------
__global__ void prep_wt(const float* __restrict__ W, const float* __restrict__ U,
                        float* __restrict__ WT, int D, int XPAD, int H)
{
    const int DHp = XPAD + H;
    const int total = 3 * H * DHp;
    int idx = blockIdx.x * blockDim.x + threadIdx.x;
    if (idx >= total) return;
    int c = idx / DHp;
    int d = idx % DHp;
    float v;
    if (d < D)          v = W[(size_t)d * (3 * H) + c];
    else if (d < XPAD)  v = 0.f;
    else                v = U[(size_t)(d - XPAD) * (3 * H) + c];
    WT[idx] = v;
}

// pad emb table to 152 cols (zeros) — MODE B only
__global__ void prep_emb(const float* __restrict__ emb, float* __restrict__ embP)
{
    int idx = blockIdx.x * blockDim.x + threadIdx.x;
    const int total = VOCAB * 152;
    if (idx >= total) return;
    int v = idx / 152, d = idx % 152;
    embP[idx] = (d < EMB_D) ? emb[(size_t)v * EMB_D + d] : 0.f;
}

// ---------------------------------------------------------------------------
// MODE A: xw[t*200+b][768] = feat[b][t][:] @ Wf   (M=409600, N=768, K=128)
//   tile 32 rows x 256 cols x K-chunk 32; 256 threads; micro 4x(4+4)
// ---------------------------------------------------------------------------
__launch_bounds__(256)
__global__ void gemm_xw(const float* __restrict__ feat, const float* __restrict__ Wf,
                        float* __restrict__ xw)
{
    __shared__ float As[32][33];      // [k][row]
    __shared__ float Ws[32][260];     // [k][col]
    const int m0 = blockIdx.x * 32;
    const int c0 = blockIdx.y * 256;
    const int tid = threadIdx.x;
    const int tx = tid & 31, ty = tid >> 5;

    float acc0[4][4] = {{0}}, acc1[4][4] = {{0}};

    for (int k0 = 0; k0 < F_DIM; k0 += 32) {
        {   // stage A (transposed): 32 rows x 32 k
            int r = tid >> 3, q = tid & 7;
            int row = m0 + r;
            int b = row % BATCH, t = row / BATCH;
            float4 v = *reinterpret_cast<const float4*>(
                feat + ((size_t)b * T_FEAT + t) * F_DIM + k0 + q * 4);
            As[q * 4 + 0][r] = v.x; As[q * 4 + 1][r] = v.y;
            As[q * 4 + 2][r] = v.z; As[q * 4 + 3][r] = v.w;
        }
        {   // stage W: 32 k x 256 cols
            int kk = tid >> 3, q = tid & 7;
            const float* src = Wf + (size_t)(k0 + kk) * 768 + c0 + q * 32;
            float* dst = &Ws[kk][q * 32];
            #pragma unroll
            for (int i = 0; i < 8; ++i)
                *reinterpret_cast<float4*>(dst + i * 4) =
                    *reinterpret_cast<const float4*>(src + i * 4);
        }
        __syncthreads();
        #pragma unroll
        for (int k = 0; k < 32; ++k) {
            float4 a  = *reinterpret_cast<float4*>(&As[k][ty * 4]);
            float4 w0 = *reinterpret_cast<float4*>(&Ws[k][tx * 4]);
            float4 w1 = *reinterpret_cast<float4*>(&Ws[k][128 + tx * 4]);
            float av[4] = {a.x, a.y, a.z, a.w};
            float w0v[4] = {w0.x, w0.y, w0.z, w0.w};
            float w1v[4] = {w1.x, w1.y, w1.z, w1.w};
            #pragma unroll
            for (int r = 0; r < 4; ++r)
                #pragma unroll
                for (int c = 0; c < 4; ++c) {
                    acc0[r][c] += av[r] * w0v[c];
                    acc1[r][c] += av[r] * w1v[c];
                }
        }
        __syncthreads();
    }
    #pragma unroll
    for (int r = 0; r < 4; ++r) {
        int row = m0 + ty * 4 + r;
        float4 o0 = {acc0[r][0], acc0[r][1], acc0[r][2], acc0[r][3]};
        float4 o1 = {acc1[r][0], acc1[r][1], acc1[r][2], acc1[r][3]};
        *reinterpret_cast<float4*>(xw + (size_t)row * 768 + c0 + tx * 4) = o0;
        *reinterpret_cast<float4*>(xw + (size_t)row * 768 + c0 + 128 + tx * 4) = o1;
    }
}

// ---------------------------------------------------------------------------
// MODE A: xc[t*200+b][600] = emb[cids[b][t]] @ Wc  (M=25600, K=150, N=600)
//   one block per 8 rows; W cols streamed from global (L2-hot)
// ---------------------------------------------------------------------------
__launch_bounds__(256)
__global__ void char_xw(const float* __restrict__ emb, const int* __restrict__ cids,
                        const float* __restrict__ Wc, float* __restrict__ xc)
{
    __shared__ float xs[8][150];
    const int row0 = blockIdx.x * 8;
    const int tid = threadIdx.x;
    for (int i = tid; i < 600; i += 256) {
        int r = i / 75, q = i % 75;
        int row = row0 + r;
        int b = row % BATCH, t = row / BATCH;
        int id = cids[(size_t)b * T_CHAR + t];
        float2 v = *reinterpret_cast<const float2*>(emb + (size_t)id * EMB_D + q * 2);
        xs[r][q * 2] = v.x; xs[r][q * 2 + 1] = v.y;
    }
    __syncthreads();
    for (int c = tid; c < 600; c += 256) {
        float acc[8] = {0, 0, 0, 0, 0, 0, 0, 0};
        for (int k = 0; k < EMB_D; ++k) {
            float w = Wc[(size_t)k * 600 + c];
            #pragma unroll
            for (int r = 0; r < 8; ++r) acc[r] += xs[r][k] * w;
        }
        #pragma unroll
        for (int r = 0; r < 8; ++r)
            xc[(size_t)(row0 + r) * 600 + c] = acc[r];
    }
}

// ---------------------------------------------------------------------------
// Merged persistent GRU (cooperative, 256 blocks x 512 threads).
// PREX=true : x-projections precomputed (xw/xc), 3-scalar prefetch.
// PREX=false: inline x-dots (r3 style, transient regs only).
// ---------------------------------------------------------------------------
template<bool PREX>
__launch_bounds__(512, 1)
__global__ void gru_both2(const float* __restrict__ feat,
                          const int*   __restrict__ cids,
                          const float* __restrict__ embP,
                          const float* __restrict__ xw,    // [T_FEAT*200][768]
                          const float* __restrict__ xc,    // [T_CHAR*200][600]
                          const float* __restrict__ WTf,   // [768][384]
                          const float* __restrict__ WTc,   // [600][352]
                          const float* __restrict__ bf0, const float* __restrict__ bf1,
                          const float* __restrict__ bc0, const float* __restrict__ bc1,
                          float* __restrict__ hfA, float* __restrict__ hfB,
                          float* __restrict__ hcA, float* __restrict__ hcB,
                          unsigned* __restrict__ flagsF,
                          unsigned* __restrict__ flagsC)
{
    __shared__ float wF[24][388];     // fused feature slice (x part used in MODE B)
    __shared__ float wC[24][356];
    __shared__ float px[256 * 5];

    const int tid = threadIdx.x;
    const int bc  = blockIdx.x & 7;
    const int uc  = blockIdx.x >> 3;
    const int bg  = bc * TBR;
    const int ugF = uc * 8;
    const bool hasChar = (uc < CBPG);
    const int ugC = uc * 8;

    for (int i = tid; i < 24 * 96; i += 512) {
        int r = i / 96, d4 = (i % 96) * 4;
        int wrow = (r >> 3) * H_FEAT + ugF + (r & 7);
        *reinterpret_cast<float4*>(&wF[r][d4]) =
            *reinterpret_cast<const float4*>(WTf + (size_t)wrow * 384 + d4);
    }
    if (hasChar) {
        for (int i = tid; i < 24 * 88; i += 512) {
            int r = i / 88, d4 = (i % 88) * 4;
            int wrow = (r >> 3) * H_CHAR + ugC + (r & 7);
            *reinterpret_cast<float4*>(&wC[r][d4]) =
                *reinterpret_cast<const float4*>(WTc + (size_t)wrow * 352 + d4);
        }
    }

    const int k = tid >> 8;
    const int pairIdx = tid & 255;
    const int j = pairIdx & 7;
    const int b = pairIdx >> 3;
    const bool valid = (b < TBR);

    const float* wzF = wF[j];
    const float* wrF = wF[8 + j];
    const float* whF = wF[16 + j];
    const float* wzC = wC[j];
    const float* wrC = wC[8 + j];
    const float* whC = wC[16 + j];

    const float bzzF = bf0[ugF + j] + bf1[ugF + j];
    const float brrF = bf0[H_FEAT + ugF + j] + bf1[H_FEAT + ugF + j];
    const float bxhF = bf0[2 * H_FEAT + ugF + j];
    const float brhF = bf1[2 * H_FEAT + ugF + j];
    float bzzC = 0.f, brrC = 0.f, bxhC = 0.f, brhC = 0.f;
    if (hasChar) {
        bzzC = bc0[ugC + j] + bc1[ugC + j];
        brrC = bc0[H_CHAR + ugC + j] + bc1[H_CHAR + ugC + j];
        bxhC = bc0[2 * H_CHAR + ugC + j];
        brhC = bc1[2 * H_CHAR + ugC + j];
    }

    unsigned* gfF = flagsF + (size_t)bc * 32 * FLAG_STRIDE;
    unsigned* gfC = flagsC + (size_t)bc * 32 * FLAG_STRIDE;
    unsigned* myF = gfF + (size_t)uc * FLAG_STRIDE;
    unsigned* myC = gfC + (size_t)uc * FLAG_STRIDE;

    __syncthreads();                   // weights staged

    // ---- preload x-contributions for t=0 ----
    float xaz = 0.f, xar = 0.f, xah = 0.f;
    float cxaz = 0.f, cxar = 0.f, cxah = 0.f;
    if constexpr (PREX) {
        if (valid && k == 0) {
            const float* p = xw + ((size_t)(bg + b)) * 768 + ugF + j;
            xaz = p[0]; xar = p[256]; xah = p[512];
            if (hasChar) {
                const float* q = xc + ((size_t)(bg + b)) * 600 + ugC + j;
                cxaz = q[0]; cxar = q[200]; cxah = q[400];
            }
        }
    } else {
        if (valid) {
            const float* xrow = feat + ((size_t)(bg + b) * T_FEAT + 0) * F_DIM + k * 64;
            #pragma unroll
            for (int i = 0; i < 16; ++i) {
                float4 xv = reinterpret_cast<const float4*>(xrow)[i];
                float4 a4 = *reinterpret_cast<const float4*>(wzF + k * 64 + 4 * i);
                float4 c4 = *reinterpret_cast<const float4*>(wrF + k * 64 + 4 * i);
                float4 e4 = *reinterpret_cast<const float4*>(whF + k * 64 + 4 * i);
                xaz += xv.x*a4.x + xv.y*a4.y + xv.z*a4.z + xv.w*a4.w;
                xar += xv.x*c4.x + xv.y*c4.y + xv.z*c4.z + xv.w*c4.w;
                xah += xv.x*e4.x + xv.y*e4.y + xv.z*e4.z + xv.w*e4.w;
            }
            if (hasChar) {
                int id0 = cids[(size_t)(bg + b) * T_CHAR + 0];
                const float* e0 = embP + (size_t)id0 * 152 + k * 76;
                #pragma unroll
                for (int i = 0; i < 19; ++i) {
                    float4 xv = reinterpret_cast<const float4*>(e0)[i];
                    float4 a4 = *reinterpret_cast<const float4*>(wzC + k * 76 + 4 * i);
                    float4 c4 = *reinterpret_cast<const float4*>(wrC + k * 76 + 4 * i);
                    float4 e4 = *reinterpret_cast<const float4*>(whC + k * 76 + 4 * i);
                    cxaz += xv.x*a4.x + xv.y*a4.y + xv.z*a4.z + xv.w*a4.w;
                    cxar += xv.x*c4.x + xv.y*c4.y + xv.z*c4.z + xv.w*c4.w;
                    cxah += xv.x*e4.x + xv.y*e4.y + xv.z*e4.z + xv.w*e4.w;
                }
            }
        }
    }

    float holdF = 0.f, holdC = 0.f;

    for (int t = 0; t < T_FEAT; ++t) {
        const float* hfin = (t & 1) ? hfB : hfA;
        float*       hfout = (t & 1) ? hfA : hfB;
        const bool doChar = hasChar && (t < T_CHAR);

        if (t > 0) {
            if (tid < 64) {
                const unsigned tgt = (unsigned)t;
                const bool needF = (tid < FBPG);
                const bool needC = hasChar && (t < T_CHAR) &&
                                   (tid >= 32) && (tid < 32 + CBPG);
                unsigned* fp = needF ? (gfF + (size_t)tid * FLAG_STRIDE)
                             : (needC ? (gfC + (size_t)(tid - 32) * FLAG_STRIDE)
                                      : nullptr);
                for (;;) {
                    unsigned v = fp ? __hip_atomic_load(fp, __ATOMIC_RELAXED,
                                                        __HIP_MEMORY_SCOPE_AGENT)
                                    : tgt;
                    if (__all((int)(v >= tgt))) break;
                    __builtin_amdgcn_s_sleep(1);
                }
            }
            __syncthreads();
            __builtin_amdgcn_fence(__ATOMIC_ACQUIRE, "agent");
        }

        // ================= FEATURE step =================
        float haz = 0.f, har = 0.f, hah = 0.f;
        if (valid) {
            const float* hrow = hfin + (size_t)(bg + b) * H_FEAT + k * 128;
            #pragma unroll 4
            for (int i = 0; i < 32; ++i) {
                float4 hv = reinterpret_cast<const float4*>(hrow)[i];
                float4 a4 = *reinterpret_cast<const float4*>(wzF + 128 + k * 128 + 4 * i);
                float4 c4 = *reinterpret_cast<const float4*>(wrF + 128 + k * 128 + 4 * i);
                float4 e4 = *reinterpret_cast<const float4*>(whF + 128 + k * 128 + 4 * i);
                haz += hv.x*a4.x + hv.y*a4.y + hv.z*a4.z + hv.w*a4.w;
                har += hv.x*c4.x + hv.y*c4.y + hv.z*c4.z + hv.w*c4.w;
                hah += hv.x*e4.x + hv.y*e4.y + hv.z*e4.z + hv.w*e4.w;
            }
        }
        const float azs = xaz + haz, ars = xar + har;
        if (valid && k == 1) {
            float* p = &px[pairIdx * 5];
            p[0] = azs; p[1] = ars; p[2] = xah; p[3] = hah;
        }
        __syncthreads();
        if (valid && k == 0) {
            const float* p = &px[pairIdx * 5];
            float az = azs + p[0];
            float ar = ars + p[1];
            float xh = xah + p[2];
            float rh = hah + p[3];
            float z = 1.f / (1.f + __expf(-(az + bzzF)));
            float r = 1.f / (1.f + __expf(-(ar + brrF)));
            float a = xh + bxhF + r * (rh + brhF);
            float hh = 1.f - 2.f / (1.f + __expf(2.f * a));
            float hnew = z * holdF + (1.f - z) * hh;
            holdF = hnew;
            __hip_atomic_store(hfout + (size_t)(bg + b) * H_FEAT + ugF + j, hnew,
                               __ATOMIC_RELAXED, __HIP_MEMORY_SCOPE_AGENT);
        }
        __syncthreads();               // drains vmcnt -> h stores visible
        if (tid == 0 && t + 1 < T_FEAT)
            __hip_atomic_store(myF, (unsigned)(t + 1),
                               __ATOMIC_RELAXED, __HIP_MEMORY_SCOPE_AGENT);

        // x-contribution for t+1
        if constexpr (PREX) {
            if (valid && k == 0 && t + 1 < T_FEAT) {
                const float* p = xw + ((size_t)(t + 1) * BATCH + (bg + b)) * 768 + ugF + j;
                xaz = p[0]; xar = p[256]; xah = p[512];
            }
        } else {
            if (valid && t + 1 < T_FEAT) {
                const float* xrow = feat + ((size_t)(bg + b) * T_FEAT + (t + 1)) * F_DIM + k * 64;
                float nz = 0.f, nr = 0.f, nh = 0.f;
                #pragma unroll
                for (int i = 0; i < 16; ++i) {
                    float4 xv = reinterpret_cast<const float4*>(xrow)[i];
                    float4 a4 = *reinterpret_cast<const float4*>(wzF + k * 64 + 4 * i);
                    float4 c4 = *reinterpret_cast<const float4*>(wrF + k * 64 + 4 * i);
                    float4 e4 = *reinterpret_cast<const float4*>(whF + k * 64 + 4 * i);
                    nz += xv.x*a4.x + xv.y*a4.y + xv.z*a4.z + xv.w*a4.w;
                    nr += xv.x*c4.x + xv.y*c4.y + xv.z*c4.z + xv.w*c4.w;
                    nh += xv.x*e4.x + xv.y*e4.y + xv.z*e4.z + xv.w*e4.w;
                }
                xaz = nz; xar = nr; xah = nh;
            }
        }

        // ================= CHAR step =================
        if (doChar) {
            const float* hcin = (t & 1) ? hcB : hcA;
            float*       hcout = (t & 1) ? hcA : hcB;

            float chaz = 0.f, char_ = 0.f, chah = 0.f;
            if (valid) {
                const float* hrow = hcin + (size_t)(bg + b) * H_CHAR + k * 100;
                #pragma unroll 5
                for (int i = 0; i < 25; ++i) {
                    float4 hv = reinterpret_cast<const float4*>(hrow)[i];
                    float4 a4 = *reinterpret_cast<const float4*>(wzC + 152 + k * 100 + 4 * i);
                    float4 c4 = *reinterpret_cast<const float4*>(wrC + 152 + k * 100 + 4 * i);
                    float4 e4 = *reinterpret_cast<const float4*>(whC + 152 + k * 100 + 4 * i);
                    chaz  += hv.x*a4.x + hv.y*a4.y + hv.z*a4.z + hv.w*a4.w;
                    char_ += hv.x*c4.x + hv.y*c4.y + hv.z*c4.z + hv.w*c4.w;
                    chah  += hv.x*e4.x + hv.y*e4.y + hv.z*e4.z + hv.w*e4.w;
                }
            }
            const float cazs = cxaz + chaz, cars = cxar + char_;
            if (valid && k == 1) {
                float* p = &px[pairIdx * 5];
                p[0] = cazs; p[1] = cars; p[2] = cxah; p[3] = chah;
            }
            __syncthreads();
            if (valid && k == 0) {
                const float* p = &px[pairIdx * 5];
                float az = cazs + p[0];
                float ar = cars + p[1];
                float xh = cxah + p[2];
                float rh = chah + p[3];
                float z = 1.f / (1.f + __expf(-(az + bzzC)));
                float r = 1.f / (1.f + __expf(-(ar + brrC)));
                float a = xh + bxhC + r * (rh + brhC);
                float hh = 1.f - 2.f / (1.f + __expf(2.f * a));
                float hnew = z * holdC + (1.f - z) * hh;
                holdC = hnew;
                __hip_atomic_store(hcout + (size_t)(bg + b) * H_CHAR + ugC + j, hnew,
                                   __ATOMIC_RELAXED, __HIP_MEMORY_SCOPE_AGENT);
            }
            __syncthreads();
            if (tid == 0 && t + 1 < T_CHAR)
                __hip_atomic_store(myC, (unsigned)(t + 1),
                                   __ATOMIC_RELAXED, __HIP_MEMORY_SCOPE_AGENT);

            if constexpr (PREX) {
                if (valid && k == 0 && t + 1 < T_CHAR) {
                    const float* p = xc + ((size_t)(t + 1) * BATCH + (bg + b)) * 600 + ugC + j;
                    cxaz = p[0]; cxar = p[200]; cxah = p[400];
                }
            } else {
                if (valid && t + 1 < T_CHAR) {
                    int idN = cids[(size_t)(bg + b) * T_CHAR + (t + 1)];
                    const float* e1 = embP + (size_t)idN * 152 + k * 76;
                    float nz = 0.f, nr = 0.f, nh = 0.f;
                    #pragma unroll
                    for (int i = 0; i < 19; ++i) {
                        float4 xv = reinterpret_cast<const float4*>(e1)[i];
                        float4 a4 = *reinterpret_cast<const float4*>(wzC + k * 76 + 4 * i);
                        float4 c4 = *reinterpret_cast<const float4*>(wrC + k * 76 + 4 * i);
                        float4 e4 = *reinterpret_cast<const float4*>(whC + k * 76 + 4 * i);
                        nz += xv.x*a4.x + xv.y*a4.y + xv.z*a4.z + xv.w*a4.w;
                        nr += xv.x*c4.x + xv.y*c4.y + xv.z*c4.z + xv.w*c4.w;
                        nh += xv.x*e4.x + xv.y*e4.y + xv.z*e4.z + xv.w*e4.w;
                    }
                    cxaz = nz; cxar = nr; cxah = nh;
                }
            }
        }
    }
}

// ---------------------------------------------------------------------------
// dense: y[row] = act(x[row] @ W + bias). ACT: 0 none, 1 relu, 2 softmax
// ---------------------------------------------------------------------------
template<int ACT>
__launch_bounds__(256)
__global__ void dense(const float* __restrict__ x, int ldx, int D,
                      const float* __restrict__ W, const float* __restrict__ bias, int N,
                      float* __restrict__ y, int ldy)
{
    __shared__ float xs[544];
    __shared__ float ys[288];
    __shared__ float red[2];
    const int row = blockIdx.x;
    const float* xr = x + (size_t)row * ldx;
    for (int i = threadIdx.x; i < D; i += blockDim.x) xs[i] = xr[i];
    __syncthreads();
    for (int j = threadIdx.x; j < N; j += blockDim.x) {
        float acc = bias[j];
        for (int d = 0; d < D; ++d) acc += xs[d] * W[(size_t)d * N + j];
        if (ACT == 1) acc = fmaxf(acc, 0.f);
        if (ACT == 2) ys[j] = acc;
        else          y[(size_t)row * ldy + j] = acc;
    }
    if (ACT == 2) {
        __syncthreads();
        if (threadIdx.x == 0) {
            float m = -1e30f;
            for (int i = 0; i < N; ++i) m = fmaxf(m, ys[i]);
            float s = 0.f;
            for (int i = 0; i < N; ++i) s += expf(ys[i] - m);
            red[0] = m; red[1] = s;
        }
        __syncthreads();
        float m = red[0], s = red[1];
        for (int j = threadIdx.x; j < N; j += blockDim.x)
            y[(size_t)row * ldy + j] = expf(ys[j] - m) / s;
    }
}

// ---------------------------------------------------------------------------
extern "C" void kernel_launch(void* const* d_in, const int* in_sizes, int n_in,
                              void* d_out, int out_size, void* d_ws, size_t ws_size,
                              hipStream_t stream)
{
    const float* feat = (const float*)d_in[1];
    const int*   cids = (const int*)  d_in[2];
    const float* emb  = (const float*)d_in[3];
    const float* Wc   = (const float*)d_in[4];
    const float* Uc   = (const float*)d_in[5];
    const float* bcb  = (const float*)d_in[6];
    const float* Wf   = (const float*)d_in[7];
    const float* Uf   = (const float*)d_in[8];
    const float* bfb  = (const float*)d_in[9];
    const float* Wfd  = (const float*)d_in[10]; const float* bfd = (const float*)d_in[11];
    const float* Wc1  = (const float*)d_in[12]; const float* bc1 = (const float*)d_in[13];
    const float* Wc2  = (const float*)d_in[14]; const float* bc2 = (const float*)d_in[15];
    const float* W1   = (const float*)d_in[16]; const float* b1  = (const float*)d_in[17];
    const float* W2   = (const float*)d_in[18]; const float* b2  = (const float*)d_in[19];
    const float* Wsm  = (const float*)d_in[20]; const float* bsm = (const float*)d_in[21];
    float* out = (float*)d_out;

    // workspace carve-up (floats); xw/xc last so MODE B works with small ws
    float* ws  = (float*)d_ws;
    float* WTf = ws; ws += 768 * 384;
    float* WTc = ws; ws += 600 * 352;
    float* embP = ws; ws += VOCAB * 152;
    float* hf0 = ws; ws += BATCH * H_FEAT;
    float* hf1 = ws; ws += BATCH * H_FEAT;
    float* hc0 = ws; ws += BATCH * H_CHAR;
    float* hc1 = ws; ws += BATCH * H_CHAR;
    float* xcat = ws; ws += BATCH * (2 * HID);
    float* tA  = ws; ws += BATCH * HID;
    float* tB  = ws; ws += BATCH * HID;
    unsigned* flagsF = (unsigned*)ws; ws += NGRP * 32 * FLAG_STRIDE;
    unsigned* flagsC = (unsigned*)ws; ws += NGRP * 32 * FLAG_STRIDE;
    float* xc = ws; ws += (size_t)T_CHAR * BATCH * 600;       // 61.4 MB
    float* xw = ws; ws += (size_t)T_FEAT * BATCH * 768;       // 1258 MB
    const size_t need = (size_t)((char*)ws - (char*)d_ws);
    const bool modeA = (ws_size >= need);

    hipMemsetAsync(hf0, 0, BATCH * H_FEAT * sizeof(float), stream);
    hipMemsetAsync(hc0, 0, BATCH * H_CHAR * sizeof(float), stream);
    hipMemsetAsync(flagsF, 0, NGRP * 32 * FLAG_STRIDE * sizeof(unsigned) * 2, stream);

    prep_wt<<<(768 * 384 + 255) / 256, 256, 0, stream>>>(Wf, Uf, WTf, 128, 128, H_FEAT);
    prep_wt<<<(600 * 352 + 255) / 256, 256, 0, stream>>>(Wc, Uc, WTc, 150, 152, H_CHAR);

    if (modeA) {
        gemm_xw<<<dim3((T_FEAT * BATCH) / 32, 3), 256, 0, stream>>>(feat, Wf, xw);
        char_xw<<<(T_CHAR * BATCH) / 8, 256, 0, stream>>>(emb, cids, Wc, xc);
    } else {
        prep_emb<<<(VOCAB * 152 + 255) / 256, 256, 0, stream>>>(emb, embP);
    }

    {
        const float* b0f = bfb;
        const float* b1f = bfb + 3 * H_FEAT;
        const float* b0c = bcb;
        const float* b1c = bcb + 3 * H_CHAR;
        void* args[] = { (void*)&feat, (void*)&cids, (void*)&embP,
                         (void*)&xw, (void*)&xc,
                         (void*)&WTf, (void*)&WTc,
                         (void*)&b0f, (void*)&b1f, (void*)&b0c, (void*)&b1c,
                         (void*)&hf0, (void*)&hf1, (void*)&hc0, (void*)&hc1,
                         (void*)&flagsF, (void*)&flagsC };
        if (modeA) {
            auto kfn = gru_both2<true>;
            hipLaunchCooperativeKernel((void*)kfn, dim3(NGRP * FBPG), dim3(512),
                                       args, 0, stream);
        } else {
            auto kfn = gru_both2<false>;
            hipLaunchCooperativeKernel((void*)kfn, dim3(NGRP * FBPG), dim3(512),
                                       args, 0, stream);
        }
    }

    // ---- heads ----
    dense<1><<<BATCH, 256, 0, stream>>>(hf0, H_FEAT, H_FEAT, Wfd, bfd, HID, xcat,       2 * HID);
    dense<1><<<BATCH, 256, 0, stream>>>(hc0, H_CHAR, H_CHAR, Wc1, bc1, HID, tA,         HID);
    dense<2><<<BATCH, 256, 0, stream>>>(tA,  HID,    HID,    Wc2, bc2, HID, xcat + HID, 2 * HID);
    dense<1><<<BATCH, 256, 0, stream>>>(xcat, 2 * HID, 2 * HID, W1, b1, HID, tB,        HID);
    dense<1><<<BATCH, 256, 0, stream>>>(tB,  HID,    HID,    W2,  b2,  HID, tA,         HID);
    dense<2><<<BATCH, 256, 0, stream>>>(tA,  HID,    HID,    Wsm, bsm, NCLS, out,       NCLS);
}